// Round 1
// baseline (451.448 us; speedup 1.0000x reference)
//
#include <hip/hip_runtime.h>
#include <hip/hip_bf16.h>
#include <math.h>

// Problem: B=8, T=2048, C=1024, H=64.
// out[b,t,h] = softmax_s( (X Wq^T)(X Wk^T)^T * C^-0.5, mask over s ) @ (X Wv^T)
//
// Round 1: correct fp32 baseline.
//   Kernel 1: Q/K/V projections. 192 threads = 3 waves (one per weight matrix),
//             16 X-rows staged in LDS (64KB), lane h owns W row (broadcast LDS reads).
//             C^-0.5 = 1/32 folded into Q at store time.
//   Kernel 2: flash attention, 32-query tile per block, 256 threads,
//             8 lanes per query row (shfl reductions), K/V/P tiles in LDS
//             padded to 68 floats/row (bank-conflict analysis in round notes).

#define T_SEQ 2048
#define EMB 1024
#define HS 64
#define NB 8
#define ROWS 16   // X rows per projection block
#define TQ 32     // query rows per attention block

__global__ __launch_bounds__(192) void proj_kernel(
    const float* __restrict__ X,
    const float* __restrict__ Wq, const float* __restrict__ Wk,
    const float* __restrict__ Wv,
    float* __restrict__ Q, float* __restrict__ K, float* __restrict__ V) {
  __shared__ float Xs[ROWS * EMB];  // 64 KB
  const int tid = threadIdx.x;
  const long row0 = (long)blockIdx.x * ROWS;

  // cooperative coalesced load of the X tile (ROWS*256 float4)
  const float4* Xg = (const float4*)(X + row0 * EMB);
  float4* Xs4 = (float4*)Xs;
  for (int i = tid; i < ROWS * 256; i += 192) Xs4[i] = Xg[i];
  __syncthreads();

  const int m = tid >> 6;   // wave id: 0=Q,1=K,2=V (wave-uniform)
  const int h = tid & 63;   // head dim owned by this lane
  const float* W = (m == 0) ? Wq : (m == 1) ? Wk : Wv;
  const float4* Wr = (const float4*)(W + h * EMB);

  float acc[ROWS];
#pragma unroll
  for (int r = 0; r < ROWS; ++r) acc[r] = 0.f;

  for (int c4 = 0; c4 < EMB / 4; ++c4) {
    float4 w = Wr[c4];
#pragma unroll
    for (int r = 0; r < ROWS; ++r) {
      float4 x = Xs4[r * 256 + c4];  // all lanes same addr -> LDS broadcast
      acc[r] += x.x * w.x + x.y * w.y + x.z * w.z + x.w * w.w;
    }
  }

  float* Outp = (m == 0) ? Q : (m == 1) ? K : V;
  const float scale = (m == 0) ? 0.03125f : 1.0f;  // fold C^-0.5 into Q
#pragma unroll
  for (int r = 0; r < ROWS; ++r) Outp[(row0 + r) * HS + h] = acc[r] * scale;
}

__global__ __launch_bounds__(256) void attn_kernel(
    const float* __restrict__ Q, const float* __restrict__ K,
    const float* __restrict__ V, const int* __restrict__ mask,
    float* __restrict__ out) {
  __shared__ float Qs[TQ][68];
  __shared__ float Ks[64][68];
  __shared__ float Vs[64][68];
  __shared__ float Ps[TQ][68];
  __shared__ int ms[64];

  const int tid = threadIdx.x;
  const int b = blockIdx.y;
  const int qt = blockIdx.x;
  const int row = tid >> 3;  // 0..31 query row in tile
  const int g = tid & 7;     // 0..7 lane group within row (same wave)
  const long qbase = ((long)b * T_SEQ + (long)qt * TQ) * HS;

  // load Q tile: TQ*16 float4
  {
    const float4* Qg = (const float4*)(Q + qbase);
    for (int i = tid; i < TQ * 16; i += 256) {
      int r = i >> 4, c4 = i & 15;
      *(float4*)&Qs[r][c4 * 4] = Qg[i];
    }
  }

  float O[8] = {0, 0, 0, 0, 0, 0, 0, 0};
  float mrow = -INFINITY, lsum = 0.f;
  const float* Kb = K + (long)b * T_SEQ * HS;
  const float* Vb = V + (long)b * T_SEQ * HS;
  const int* mb = mask + b * T_SEQ;

  for (int kt = 0; kt < T_SEQ / 64; ++kt) {
    __syncthreads();  // previous PV done before overwriting K/V/P
    const float4* Kg = (const float4*)(Kb + (long)kt * 64 * HS);
    const float4* Vg = (const float4*)(Vb + (long)kt * 64 * HS);
    for (int i = tid; i < 1024; i += 256) {
      int r = i >> 4, c4 = i & 15;
      *(float4*)&Ks[r][c4 * 4] = Kg[i];
      *(float4*)&Vs[r][c4 * 4] = Vg[i];
    }
    if (tid < 64) ms[tid] = mb[kt * 64 + tid];
    __syncthreads();

    // ---- S phase: this thread's keys j = jj*8 + g (stride-8: conflict-free Ks reads)
    float p[8];
    float mt = -INFINITY;
#pragma unroll
    for (int jj = 0; jj < 8; ++jj) {
      const int j = jj * 8 + g;
      float4 a = {0, 0, 0, 0};
#pragma unroll
      for (int c4 = 0; c4 < 16; ++c4) {
        float4 q = *(const float4*)&Qs[row][c4 * 4];
        float4 k = *(const float4*)&Ks[j][c4 * 4];
        a.x += q.x * k.x; a.y += q.y * k.y;
        a.z += q.z * k.z; a.w += q.w * k.w;
      }
      float s = (a.x + a.y) + (a.z + a.w);
      s = ms[j] ? -INFINITY : s;
      p[jj] = s;
      mt = fmaxf(mt, s);
    }
    // row max across the 8 lanes of this row
    for (int d = 1; d < 8; d <<= 1) mt = fmaxf(mt, __shfl_xor(mt, d, 64));
    const float mnew = fmaxf(mrow, mt);
    const float alpha = expf(mrow - mnew);  // mrow=-inf first tile -> 0

    float psum = 0.f;
#pragma unroll
    for (int jj = 0; jj < 8; ++jj) {
      p[jj] = expf(p[jj] - mnew);  // masked: exp(-inf)=0
      psum += p[jj];
      Ps[row][jj * 8 + g] = p[jj];
    }
    lsum = lsum * alpha + psum;  // per-lane partial l (alpha row-uniform)
    mrow = mnew;
    __syncthreads();  // P visible to all lanes of the row

    // ---- PV phase: this thread owns h = g*8 .. g*8+7
#pragma unroll
    for (int hh = 0; hh < 8; ++hh) O[hh] *= alpha;
    const int h0 = g * 8;
    for (int j = 0; j < 64; ++j) {
      const float pv = Ps[row][j];
      float4 v0 = *(const float4*)&Vs[j][h0];
      float4 v1 = *(const float4*)&Vs[j][h0 + 4];
      O[0] += pv * v0.x; O[1] += pv * v0.y;
      O[2] += pv * v0.z; O[3] += pv * v0.w;
      O[4] += pv * v1.x; O[5] += pv * v1.y;
      O[6] += pv * v1.z; O[7] += pv * v1.w;
    }
  }

  // total l across the row's 8 lanes (each holds a partial sum)
  for (int d = 1; d < 8; d <<= 1) lsum += __shfl_xor(lsum, d, 64);
  const float inv = 1.0f / lsum;

  float4 o0 = {O[0] * inv, O[1] * inv, O[2] * inv, O[3] * inv};
  float4 o1 = {O[4] * inv, O[5] * inv, O[6] * inv, O[7] * inv};
  float* op = out + qbase + (long)row * HS + g * 8;
  *(float4*)op = o0;
  *(float4*)(op + 4) = o1;
}

extern "C" void kernel_launch(void* const* d_in, const int* in_sizes, int n_in,
                              void* d_out, int out_size, void* d_ws, size_t ws_size,
                              hipStream_t stream) {
  const float* X  = (const float*)d_in[0];
  const float* Wq = (const float*)d_in[1];
  const float* Wk = (const float*)d_in[2];
  const float* Wv = (const float*)d_in[3];
  const int* mask = (const int*)d_in[4];  // bool -> int32 per harness convention
  float* outp = (float*)d_out;

  // workspace: Q,K,V each NB*T_SEQ*HS floats = 4MB -> 12MB total
  float* Qw = (float*)d_ws;
  float* Kw = Qw + (long)NB * T_SEQ * HS;
  float* Vw = Kw + (long)NB * T_SEQ * HS;

  proj_kernel<<<(NB * T_SEQ) / ROWS, 192, 0, stream>>>(X, Wq, Wk, Wv, Qw, Kw, Vw);
  attn_kernel<<<dim3(T_SEQ / TQ, NB), 256, 0, stream>>>(Qw, Kw, Vw, mask, outp);
}

// Round 2
// 75.676 us; speedup vs baseline: 5.9655x; 5.9655x over previous
//
#include <hip/hip_runtime.h>
#include <hip/hip_bf16.h>
#include <math.h>

// B=8, T=2048, C=1024, H=64.
// out = softmax( (X Wq^T)(X Wk^T)^T * C^-0.5, key mask ) @ (X Wv^T)
//
// Round 2: bf16 MFMA pipeline.
//  k1 convw:  W* fp32 -> bf16 (Wq pre-scaled by 1/32)
//  k2 proj:   Q/K/V = X @ W^T via mfma_f32_16x16x32_bf16, X fp32->bf16 LDS staged
//  k3 transv: V -> V^T (bf16) so PV's B-operand is a row-read
//  k4 attn:   flash, 64 q/block, 4 waves x 16 q each, swapped QK^T (S^T = K Q^T)
//             -> per-lane softmax; P -> LDS bf16 (within-wave, barrier-free); PV MFMA.
// MFMA layout notes: only C/D map (col=lane&15, row=4*(lane>>4)+reg) is relied on
// exactly; A/B k-ordering cancels because both operands use the same (hi,e)->k map.

#define T_SEQ 2048
#define EMB 1024
#define HS 64
#define NB 8

typedef __attribute__((ext_vector_type(8))) short short8;
typedef __attribute__((ext_vector_type(4))) float f32x4;
typedef unsigned short ushort_t;

static __device__ inline ushort_t f2bf(float f) {
  union { float f; unsigned u; } v; v.f = f;
  unsigned r = v.u + 0x7FFF + ((v.u >> 16) & 1);  // RNE
  return (ushort_t)(r >> 16);
}
static __device__ inline unsigned pk2(float a, float b) {
  return (unsigned)f2bf(a) | ((unsigned)f2bf(b) << 16);
}

// ---------------- k1: W conversion (48 blocks x 256 thr) ----------------
__global__ __launch_bounds__(256) void convw_kernel(
    const float* __restrict__ Wq, const float* __restrict__ Wk,
    const float* __restrict__ Wv, ushort_t* __restrict__ Wb) {
  const int m = blockIdx.x >> 4;       // 0=Q 1=K 2=V
  const int blk = blockIdx.x & 15;
  const float* src = (m == 0) ? Wq : (m == 1) ? Wk : Wv;
  const float scale = (m == 0) ? 0.03125f : 1.0f;  // fold C^-0.5 into Wq
  const int base = blk * 4096 + threadIdx.x * 16;
  ushort_t* dst = Wb + m * 65536;
  ushort_t tmp[16];
#pragma unroll
  for (int j = 0; j < 4; ++j) {
    float4 x = *(const float4*)(src + base + j * 4);
    tmp[j * 4 + 0] = f2bf(x.x * scale);
    tmp[j * 4 + 1] = f2bf(x.y * scale);
    tmp[j * 4 + 2] = f2bf(x.z * scale);
    tmp[j * 4 + 3] = f2bf(x.w * scale);
  }
  *(short8*)(dst + base) = *(short8*)tmp;
  *(short8*)(dst + base + 8) = *(short8*)(tmp + 8);
}

// ---------------- k2: projections (512 blocks x 256 thr) ----------------
// block = 32 X-rows; wave w owns 48 output cols (3 16-col tiles across Q/K/V).
__global__ __launch_bounds__(256) void proj_kernel(
    const float* __restrict__ X, const ushort_t* __restrict__ Wb,
    ushort_t* __restrict__ Qb, ushort_t* __restrict__ Kb,
    ushort_t* __restrict__ Vb) {
  __shared__ __align__(16) ushort_t Xs[32 * 72];
  const int tid = threadIdx.x;
  const int lane = tid & 63, w = tid >> 6;
  const int l15 = lane & 15, hi = lane >> 4;
  const long rbase = (long)blockIdx.x * 32;

  const int srow = tid >> 3, sc = (tid & 7) * 8;  // staging: 8 f32 per thread
  const float* Xg = X + (rbase + srow) * EMB + sc;

  float4 xr0 = *(const float4*)(Xg);
  float4 xr1 = *(const float4*)(Xg + 4);

  const ushort_t* Wrow[3];
#pragma unroll
  for (int t = 0; t < 3; ++t) {
    const int ht = 3 * w + t, m = ht >> 2, hs = ht & 3;
    Wrow[t] = Wb + m * 65536 + (hs * 16 + l15) * 1024;
  }
  short8 wf[2][6];
#pragma unroll
  for (int t = 0; t < 3; ++t) {
    wf[0][2 * t + 0] = *(const short8*)(Wrow[t] + hi * 8);
    wf[0][2 * t + 1] = *(const short8*)(Wrow[t] + 32 + hi * 8);
  }

  f32x4 acc[2][3];
#pragma unroll
  for (int rt = 0; rt < 2; ++rt)
#pragma unroll
    for (int t = 0; t < 3; ++t) acc[rt][t] = (f32x4){0.f, 0.f, 0.f, 0.f};

#pragma unroll
  for (int s = 0; s < 16; ++s) {
    __syncthreads();
    {  // stage X chunk (cvt fp32->bf16)
      ushort_t tmp[8];
      tmp[0] = f2bf(xr0.x); tmp[1] = f2bf(xr0.y);
      tmp[2] = f2bf(xr0.z); tmp[3] = f2bf(xr0.w);
      tmp[4] = f2bf(xr1.x); tmp[5] = f2bf(xr1.y);
      tmp[6] = f2bf(xr1.z); tmp[7] = f2bf(xr1.w);
      *(short8*)(Xs + srow * 72 + sc) = *(short8*)tmp;
    }
    if (s < 15) {  // prefetch next X chunk (HBM, in flight through compute)
      xr0 = *(const float4*)(Xg + (s + 1) * 64);
      xr1 = *(const float4*)(Xg + (s + 1) * 64 + 4);
    }
    __syncthreads();
    if (s < 15) {  // prefetch next W frags (L2-hot)
#pragma unroll
      for (int t = 0; t < 3; ++t) {
        wf[(s + 1) & 1][2 * t + 0] =
            *(const short8*)(Wrow[t] + (s + 1) * 64 + hi * 8);
        wf[(s + 1) & 1][2 * t + 1] =
            *(const short8*)(Wrow[t] + (s + 1) * 64 + 32 + hi * 8);
      }
    }
#pragma unroll
    for (int rt = 0; rt < 2; ++rt) {
      short8 a0 = *(const short8*)(Xs + (rt * 16 + l15) * 72 + hi * 8);
      short8 a1 = *(const short8*)(Xs + (rt * 16 + l15) * 72 + 32 + hi * 8);
#pragma unroll
      for (int t = 0; t < 3; ++t) {
        acc[rt][t] = __builtin_amdgcn_mfma_f32_16x16x32_bf16(
            a0, wf[s & 1][2 * t + 0], acc[rt][t], 0, 0, 0);
        acc[rt][t] = __builtin_amdgcn_mfma_f32_16x16x32_bf16(
            a1, wf[s & 1][2 * t + 1], acc[rt][t], 0, 0, 0);
      }
    }
  }

  // epilogue: D col=l15 (head col), row=4*hi+reg (X row)
  ushort_t* outs[3] = {Qb, Kb, Vb};
#pragma unroll
  for (int rt = 0; rt < 2; ++rt)
#pragma unroll
    for (int t = 0; t < 3; ++t) {
      const int ht = 3 * w + t, m = ht >> 2, hs = ht & 3;
#pragma unroll
      for (int r = 0; r < 4; ++r) {
        const long row = rbase + rt * 16 + 4 * hi + r;
        outs[m][row * 64 + hs * 16 + l15] = f2bf(acc[rt][t][r]);
      }
    }
}

// ---------------- k3: V transpose (32x8 blocks x 256 thr) ----------------
__global__ __launch_bounds__(256) void transv_kernel(
    const ushort_t* __restrict__ Vb, ushort_t* __restrict__ Vtb) {
  __shared__ __align__(16) ushort_t Ls[64 * 72];
  const int tid = threadIdx.x;
  const int b = blockIdx.y, kt = blockIdx.x;
  const ushort_t* src = Vb + ((long)b * T_SEQ + kt * 64) * 64;
#pragma unroll
  for (int p = 0; p < 2; ++p) {
    const int i = tid + p * 256;
    const int row = i >> 3, c = (i & 7) * 8;
    *(short8*)(Ls + row * 72 + c) = *(const short8*)(src + row * 64 + c);
  }
  __syncthreads();
  ushort_t* dst = Vtb + (long)b * HS * T_SEQ + kt * 64;
#pragma unroll
  for (int p = 0; p < 2; ++p) {
    const int j = tid + p * 256;
    const int h = j >> 3, kc = (j & 7) * 8;
    ushort_t tmp[8];
#pragma unroll
    for (int e = 0; e < 8; ++e) tmp[e] = Ls[(kc + e) * 72 + h];
    *(short8*)(dst + h * T_SEQ + kc) = *(short8*)tmp;
  }
}

// ---------------- k4: attention (32x8 blocks x 256 thr) ----------------
__global__ __launch_bounds__(256) void attn_kernel(
    const ushort_t* __restrict__ Qb, const ushort_t* __restrict__ Kb,
    const ushort_t* __restrict__ Vtb, const int* __restrict__ mask,
    float* __restrict__ out) {
  __shared__ __align__(16) float biasLds[64];
  __shared__ __align__(16) ushort_t Ks[64 * 72];
  __shared__ __align__(16) ushort_t Vs[64 * 72];
  __shared__ __align__(16) ushort_t Ps[64 * 72];

  const int tid = threadIdx.x;
  const int lane = tid & 63, w = tid >> 6;
  const int l15 = lane & 15, hi = lane >> 4;
  const int b = blockIdx.y, qb = blockIdx.x;

  // Q fragments for this wave's 16 queries (held whole kernel)
  const ushort_t* Qrow = Qb + (long)(b * T_SEQ + qb * 64 + w * 16 + l15) * 64;
  const short8 qf0 = *(const short8*)(Qrow + hi * 8);
  const short8 qf1 = *(const short8*)(Qrow + 32 + hi * 8);

  const int srow = tid >> 3, sc = (tid & 7) * 8;
  const int srow2 = srow + 32;
  const ushort_t* Kg = Kb + (long)b * T_SEQ * 64;
  const ushort_t* Vg = Vtb + (long)b * HS * T_SEQ;
  const int* mb = mask + b * T_SEQ;

  // prologue: issue tile-0 loads (K rows, V^T rows stage identically)
  short8 rk1 = *(const short8*)(Kg + srow * 64 + sc);
  short8 rk2 = *(const short8*)(Kg + srow2 * 64 + sc);
  short8 rv1 = *(const short8*)(Vg + srow * T_SEQ + sc);
  short8 rv2 = *(const short8*)(Vg + srow2 * T_SEQ + sc);
  int mi = (tid < 64) ? mb[tid] : 0;

  f32x4 O[4];
#pragma unroll
  for (int ht = 0; ht < 4; ++ht) O[ht] = (f32x4){0.f, 0.f, 0.f, 0.f};
  float mrow = -1e30f, lsum = 0.f;

  for (int t = 0; t < 32; ++t) {
    __syncthreads();  // previous compute done reading LDS
    *(short8*)(Ks + srow * 72 + sc) = rk1;
    *(short8*)(Ks + srow2 * 72 + sc) = rk2;
    *(short8*)(Vs + srow * 72 + sc) = rv1;
    *(short8*)(Vs + srow2 * 72 + sc) = rv2;
    if (tid < 64) biasLds[tid] = mi ? -1e30f : 0.f;
    if (t < 31) {  // issue next-tile loads (L2-resident, fly under compute)
      const int kb2 = (t + 1) * 64;
      rk1 = *(const short8*)(Kg + (kb2 + srow) * 64 + sc);
      rk2 = *(const short8*)(Kg + (kb2 + srow2) * 64 + sc);
      rv1 = *(const short8*)(Vg + srow * T_SEQ + kb2 + sc);
      rv2 = *(const short8*)(Vg + srow2 * T_SEQ + kb2 + sc);
      mi = (tid < 64) ? mb[kb2 + tid] : 0;
    }
    __syncthreads();  // staged tile visible

    // ---- S^T = K.Q^T : col(l15)=query, row(4*hi+reg)=key
    f32x4 s[4];
#pragma unroll
    for (int kt = 0; kt < 4; ++kt) {
      short8 k0 = *(const short8*)(Ks + (kt * 16 + l15) * 72 + hi * 8);
      short8 k1 = *(const short8*)(Ks + (kt * 16 + l15) * 72 + 32 + hi * 8);
      f32x4 z = {0.f, 0.f, 0.f, 0.f};
      s[kt] = __builtin_amdgcn_mfma_f32_16x16x32_bf16(k0, qf0, z, 0, 0, 0);
      s[kt] = __builtin_amdgcn_mfma_f32_16x16x32_bf16(k1, qf1, s[kt], 0, 0, 0);
      f32x4 bb = *(const f32x4*)(biasLds + kt * 16 + hi * 4);
      s[kt] += bb;  // key-mask bias (0 or -1e30)
    }

    // ---- per-lane online softmax for query w*16+l15 over its 16 keys
    float mt = -1e30f;
#pragma unroll
    for (int kt = 0; kt < 4; ++kt)
#pragma unroll
      for (int r = 0; r < 4; ++r) mt = fmaxf(mt, s[kt][r]);
    mt = fmaxf(mt, __shfl_xor(mt, 16, 64));
    mt = fmaxf(mt, __shfl_xor(mt, 32, 64));
    const float mnew = fmaxf(mrow, mt);
    const float alpha = __expf(mrow - mnew);
    float psum = 0.f;
#pragma unroll
    for (int kt = 0; kt < 4; ++kt) {
      const float p0 = __expf(s[kt][0] - mnew);
      const float p1 = __expf(s[kt][1] - mnew);
      const float p2 = __expf(s[kt][2] - mnew);
      const float p3 = __expf(s[kt][3] - mnew);
      psum += (p0 + p1) + (p2 + p3);
      *(unsigned*)(Ps + (w * 16 + l15) * 72 + kt * 16 + hi * 4) = pk2(p0, p1);
      *(unsigned*)(Ps + (w * 16 + l15) * 72 + kt * 16 + hi * 4 + 2) = pk2(p2, p3);
    }
    lsum = lsum * alpha + psum;
    mrow = mnew;

    // ---- rescale O (O row = query 4*hi+r -> fetch that query's alpha)
#pragma unroll
    for (int r = 0; r < 4; ++r) {
      const float ar = __shfl(alpha, 4 * hi + r, 64);
#pragma unroll
      for (int ht = 0; ht < 4; ++ht) O[ht][r] *= ar;
    }

    // ---- PV: O += P.V  (A = P rows, B = V^T rows; within-wave P reuse)
    short8 pa0 = *(const short8*)(Ps + (w * 16 + l15) * 72 + hi * 8);
    short8 pa1 = *(const short8*)(Ps + (w * 16 + l15) * 72 + 32 + hi * 8);
#pragma unroll
    for (int ht = 0; ht < 4; ++ht) {
      short8 v0 = *(const short8*)(Vs + (ht * 16 + l15) * 72 + hi * 8);
      short8 v1 = *(const short8*)(Vs + (ht * 16 + l15) * 72 + 32 + hi * 8);
      O[ht] = __builtin_amdgcn_mfma_f32_16x16x32_bf16(pa0, v0, O[ht], 0, 0, 0);
      O[ht] = __builtin_amdgcn_mfma_f32_16x16x32_bf16(pa1, v1, O[ht], 0, 0, 0);
    }
  }

  lsum += __shfl_xor(lsum, 16, 64);
  lsum += __shfl_xor(lsum, 32, 64);
  const float inv = 1.0f / lsum;
  float* ob = out + (long)(b * T_SEQ + qb * 64 + w * 16) * 64;
#pragma unroll
  for (int r = 0; r < 4; ++r) {
    const float lr = __shfl(inv, 4 * hi + r, 64);
#pragma unroll
    for (int ht = 0; ht < 4; ++ht)
      ob[(4 * hi + r) * 64 + ht * 16 + l15] = O[ht][r] * lr;
  }
}

// ---------------- launch ----------------
extern "C" void kernel_launch(void* const* d_in, const int* in_sizes, int n_in,
                              void* d_out, int out_size, void* d_ws, size_t ws_size,
                              hipStream_t stream) {
  const float* X  = (const float*)d_in[0];
  const float* Wq = (const float*)d_in[1];
  const float* Wk = (const float*)d_in[2];
  const float* Wv = (const float*)d_in[3];
  const int* mask = (const int*)d_in[4];
  float* outp = (float*)d_out;

  const long NT = (long)NB * T_SEQ * HS;  // 1,048,576 elems
  ushort_t* wsb = (ushort_t*)d_ws;
  ushort_t* Qb  = wsb;            // 2 MB
  ushort_t* Kb  = wsb + NT;       // 2 MB
  ushort_t* Vb  = wsb + 2 * NT;   // 2 MB
  ushort_t* Vtb = wsb + 3 * NT;   // 2 MB
  ushort_t* Wb  = wsb + 4 * NT;   // 384 KB

  convw_kernel<<<48, 256, 0, stream>>>(Wq, Wk, Wv, Wb);
  proj_kernel<<<(NB * T_SEQ) / 32, 256, 0, stream>>>(X, Wb, Qb, Kb, Vb);
  transv_kernel<<<dim3(T_SEQ / 64, NB), 256, 0, stream>>>(Vb, Vtb);
  attn_kernel<<<dim3(T_SEQ / 64, NB), 256, 0, stream>>>(Qb, Kb, Vtb, mask, outp);
}